// Round 1
// baseline (945.712 us; speedup 1.0000x reference)
//
#include <hip/hip_runtime.h>
#include <stdint.h>

#define HID     128
#define OUTC    10
#define NGRAPH  512

// ---------------------------------------------------------------------------
// int64-vs-int32 layout detection for integer inputs.
// Reference creates int64; harness doc says cast to const int*. Detect which
// layout is actually present: if data is little-endian int64 with values
// < 2^31, every odd int32 word is 0.
// ---------------------------------------------------------------------------
__global__ void detect64_kernel(const int* __restrict__ ei, int* __restrict__ flag) {
    if (blockIdx.x == 0 && threadIdx.x == 0) {
        int is64 = 1;
        for (int i = 0; i < 128; ++i) {
            if (ei[2 * i + 1] != 0) { is64 = 0; break; }
        }
        *flag = is64;
    }
}

__device__ __forceinline__ int fetch_idx(const int* __restrict__ p, long j, int f64) {
    return p[f64 ? (j << 1) : j];
}

// ---------------------------------------------------------------------------
// CSR build: in-degree count, exclusive scan, scatter fill
// ---------------------------------------------------------------------------
__global__ void deg_kernel(const int* __restrict__ ei, const int* __restrict__ flag,
                           int* __restrict__ deg, long E) {
    long e = (long)blockIdx.x * blockDim.x + threadIdx.x;
    if (e >= E) return;
    int f = *flag;
    int d = fetch_idx(ei, E + e, f);
    atomicAdd(&deg[d], 1);
}

__global__ void __launch_bounds__(1024) scan_kernel(const int* __restrict__ deg,
                                                    int* __restrict__ ofs, int n) {
    __shared__ int wsum[16];
    __shared__ int carry_s;
    __shared__ int chunk_tot;
    const int tid  = threadIdx.x;
    const int lane = tid & 63;
    const int wid  = tid >> 6;
    if (tid == 0) carry_s = 0;
    __syncthreads();
    const int CHUNK = 4096;  // 1024 threads x 4
    for (int base = 0; base < n; base += CHUNK) {
        int idx = base + tid * 4;
        int v[4];
#pragma unroll
        for (int j = 0; j < 4; ++j) v[j] = (idx + j < n) ? deg[idx + j] : 0;
        int s1 = v[0] + v[1] + v[2] + v[3];
        // wave inclusive scan of per-thread sums
        int inc = s1;
#pragma unroll
        for (int d = 1; d < 64; d <<= 1) {
            int t = __shfl_up(inc, d, 64);
            if (lane >= d) inc += t;
        }
        if (lane == 63) wsum[wid] = inc;
        __syncthreads();
        if (wid == 0) {
            int ws = (lane < 16) ? wsum[lane] : 0;
            int winc = ws;
#pragma unroll
            for (int d = 1; d < 16; d <<= 1) {
                int t = __shfl_up(winc, d, 64);
                if (lane >= d) winc += t;
            }
            if (lane == 15) chunk_tot = winc;          // total of this chunk
            if (lane < 16) wsum[lane] = winc - ws;     // exclusive wave prefix
        }
        __syncthreads();
        int excl = carry_s + wsum[wid] + (inc - s1);
        int run = excl;
#pragma unroll
        for (int j = 0; j < 4; ++j) {
            if (idx + j < n) ofs[idx + j] = run;
            run += v[j];
        }
        __syncthreads();                 // everyone has read carry_s
        if (tid == 0) carry_s += chunk_tot;
        __syncthreads();
    }
    if (tid == 0) ofs[n] = carry_s;
}

__global__ void dinv_kernel(const int* __restrict__ deg, float* __restrict__ dinv, int n) {
    int i = blockIdx.x * blockDim.x + threadIdx.x;
    if (i < n) dinv[i] = rsqrtf((float)deg[i] + 1.0f);
}

__global__ void fill_kernel(const int* __restrict__ ei, const int* __restrict__ flag,
                            const int* __restrict__ ofs, int* __restrict__ cnt,
                            int* __restrict__ col, long E) {
    long e = (long)blockIdx.x * blockDim.x + threadIdx.x;
    if (e >= E) return;
    int f = *flag;
    int s = fetch_idx(ei, e, f);
    int d = fetch_idx(ei, E + e, f);
    int pos = ofs[d] + atomicAdd(&cnt[d], 1);
    col[pos] = s;
}

// ---------------------------------------------------------------------------
// hs = (A @ W) * dinv[:,None]   — fp32 SGEMM, 64x128 tile, 8x8 per thread
// ---------------------------------------------------------------------------
__global__ void __launch_bounds__(128) gemm_scale_kernel(
        const float* __restrict__ A, const float* __restrict__ W,
        const float* __restrict__ dinv, float* __restrict__ out, int n) {
    __shared__ float At[16][68];    // transposed A chunk, padded (write-conflict-free)
    __shared__ float Bs[16][128];   // W chunk
    const int tid  = threadIdx.x;
    const int tx   = tid & 15;      // 16 col groups x 8 cols
    const int ty   = tid >> 4;      // 8 row groups x 8 rows
    const int brow = blockIdx.x * 64;

    float acc[8][8];
#pragma unroll
    for (int i = 0; i < 8; ++i)
#pragma unroll
        for (int j = 0; j < 8; ++j) acc[i][j] = 0.f;

    for (int k0 = 0; k0 < 128; k0 += 16) {
#pragma unroll
        for (int p = 0; p < 2; ++p) {
            int flat = tid + p * 128;     // [0,256): 64 rows x 4 float4
            int r    = flat >> 2;
            int k4   = flat & 3;
            int row  = brow + r;
            if (row >= n) row = n - 1;    // clamp (stores are guarded)
            const float4 v = *(const float4*)(A + (size_t)row * HID + k0 + k4 * 4);
            At[k4 * 4 + 0][r] = v.x;
            At[k4 * 4 + 1][r] = v.y;
            At[k4 * 4 + 2][r] = v.z;
            At[k4 * 4 + 3][r] = v.w;
        }
#pragma unroll
        for (int p = 0; p < 4; ++p) {
            int flat = tid + p * 128;     // [0,512) float4s of 16x128 chunk
            int kk   = flat >> 5;
            int c4   = flat & 31;
            *(float4*)&Bs[kk][c4 * 4] =
                *(const float4*)(W + (size_t)(k0 + kk) * HID + c4 * 4);
        }
        __syncthreads();
#pragma unroll
        for (int kk = 0; kk < 16; ++kk) {
            float a[8], b[8];
            *(float4*)&a[0] = *(const float4*)&At[kk][ty * 8];
            *(float4*)&a[4] = *(const float4*)&At[kk][ty * 8 + 4];
            *(float4*)&b[0] = *(const float4*)&Bs[kk][tx * 8];
            *(float4*)&b[4] = *(const float4*)&Bs[kk][tx * 8 + 4];
#pragma unroll
            for (int i = 0; i < 8; ++i)
#pragma unroll
                for (int j = 0; j < 8; ++j)
                    acc[i][j] = fmaf(a[i], b[j], acc[i][j]);
        }
        __syncthreads();
    }

#pragma unroll
    for (int i = 0; i < 8; ++i) {
        int row = brow + ty * 8 + i;
        if (row < n) {
            float dn = dinv[row];
            float4 o0 = make_float4(acc[i][0] * dn, acc[i][1] * dn,
                                    acc[i][2] * dn, acc[i][3] * dn);
            float4 o1 = make_float4(acc[i][4] * dn, acc[i][5] * dn,
                                    acc[i][6] * dn, acc[i][7] * dn);
            *(float4*)(out + (size_t)row * HID + tx * 8)     = o0;
            *(float4*)(out + (size_t)row * HID + tx * 8 + 4) = o1;
        }
    }
}

// ---------------------------------------------------------------------------
// out[d] = maybe_relu( dinv[d] * (hs[d] + sum_{e->d} hs[src]) + bias )
// one wave per node, lane = 2 channels
// ---------------------------------------------------------------------------
__global__ void __launch_bounds__(256) agg_kernel(
        const float* __restrict__ hs, const float* __restrict__ dinv,
        const int* __restrict__ ofs, const int* __restrict__ col,
        const float* __restrict__ bias, float* __restrict__ out,
        int n, int do_relu) {
    int node = blockIdx.x * 4 + (threadIdx.x >> 6);
    if (node >= n) return;
    int lane = threadIdx.x & 63;
    const float2* __restrict__ h2 = (const float2*)hs;

    float2 acc = h2[(size_t)node * 64 + lane];   // self term (hs already *dinv)
    int e0 = ofs[node], e1 = ofs[node + 1];
    for (int e = e0; e < e1; ++e) {
        int s = col[e];
        float2 v = h2[(size_t)s * 64 + lane];
        acc.x += v.x;
        acc.y += v.y;
    }
    float dn = dinv[node];
    float2 b = ((const float2*)bias)[lane];
    float ox = fmaf(acc.x, dn, b.x);
    float oy = fmaf(acc.y, dn, b.y);
    if (do_relu) { ox = fmaxf(ox, 0.f); oy = fmaxf(oy, 0.f); }
    ((float2*)out)[(size_t)node * 64 + lane] = make_float2(ox, oy);
}

// ---------------------------------------------------------------------------
// pooling: batch is sorted -> segment boundaries, then block-per-graph mean
// ---------------------------------------------------------------------------
__global__ void boundary_kernel(const int* __restrict__ batch, const int* __restrict__ flag,
                                int* __restrict__ gstart, int n) {
    int i = blockIdx.x * blockDim.x + threadIdx.x;
    if (i >= n) return;
    int f = *flag;
    int b  = fetch_idx(batch, i, f);
    int bp = (i == 0) ? -1 : fetch_idx(batch, i - 1, f);
    for (int g = bp + 1; g <= b; ++g) gstart[g] = i;
    if (i == n - 1) {
        for (int g = b + 1; g <= NGRAPH; ++g) gstart[g] = n;
    }
}

__global__ void __launch_bounds__(128) pool_kernel(const float* __restrict__ h,
                                                   const int* __restrict__ gstart,
                                                   float* __restrict__ pooled) {
    int g = blockIdx.x, c = threadIdx.x;
    int s = gstart[g], e = gstart[g + 1];
    float acc = 0.f;
    for (int i = s; i < e; ++i) acc += h[(size_t)i * HID + c];
    float cnt = (float)(e - s);
    pooled[g * HID + c] = acc / fmaxf(cnt, 1.f);
}

__global__ void __launch_bounds__(128) mlp_kernel(
        const float* __restrict__ pooled,
        const float* __restrict__ W1, const float* __restrict__ b1,
        const float* __restrict__ W2, const float* __restrict__ b2,
        float* __restrict__ out) {
    __shared__ float p[HID];
    __shared__ float hid[HID];
    int g = blockIdx.x, c = threadIdx.x;
    p[c] = pooled[g * HID + c];
    __syncthreads();
    float a = b1[c];
#pragma unroll 8
    for (int k = 0; k < HID; ++k) a = fmaf(p[k], W1[k * HID + c], a);
    hid[c] = fmaxf(a, 0.f);
    __syncthreads();
    if (c < OUTC) {
        float o = b2[c];
#pragma unroll 8
        for (int k = 0; k < HID; ++k) o = fmaf(hid[k], W2[k * OUTC + c], o);
        out[g * OUTC + c] = o;
    }
}

// ---------------------------------------------------------------------------
extern "C" void kernel_launch(void* const* d_in, const int* in_sizes, int n_in,
                              void* d_out, int out_size, void* d_ws, size_t ws_size,
                              hipStream_t stream) {
    const float* x   = (const float*)d_in[0];
    const int*   ei  = (const int*)d_in[1];
    const int*   bat = (const int*)d_in[2];
    const float* Wc0 = (const float*)d_in[3];
    const float* bc0 = (const float*)d_in[4];
    const float* Wc1 = (const float*)d_in[5];
    const float* bc1 = (const float*)d_in[6];
    const float* Wc2 = (const float*)d_in[7];
    const float* bc2 = (const float*)d_in[8];
    const float* W1  = (const float*)d_in[9];
    const float* b1  = (const float*)d_in[10];
    const float* W2  = (const float*)d_in[11];
    const float* b2  = (const float*)d_in[12];
    float* out = (float*)d_out;

    const int  n = in_sizes[0] / HID;
    const long E = in_sizes[1] / 2;

    // workspace carve-out (all recomputed every call)
    char* w = (char*)d_ws;
    size_t off = 0;
    auto carve = [&](size_t bytes) {
        void* p = w + off;
        off += (bytes + 255) & ~(size_t)255;
        return p;
    };
    int*   flag   = (int*)carve(4);
    int*   deg    = (int*)carve((size_t)n * 4);
    int*   ofs    = (int*)carve((size_t)(n + 1) * 4);
    int*   cnt    = (int*)carve((size_t)n * 4);
    float* dinv   = (float*)carve((size_t)n * 4);
    int*   gstart = (int*)carve((NGRAPH + 1) * 4);
    int*   col    = (int*)carve((size_t)E * 4);
    float* h0     = (float*)carve((size_t)n * HID * 4);
    float* h1     = (float*)carve((size_t)n * HID * 4);
    float* pooled = (float*)carve((size_t)NGRAPH * HID * 4);

    hipMemsetAsync(deg, 0, (size_t)n * 4, stream);
    hipMemsetAsync(cnt, 0, (size_t)n * 4, stream);

    detect64_kernel<<<1, 64, 0, stream>>>(ei, flag);

    const int eb = (int)((E + 255) / 256);
    deg_kernel<<<eb, 256, 0, stream>>>(ei, flag, deg, E);
    scan_kernel<<<1, 1024, 0, stream>>>(deg, ofs, n);
    dinv_kernel<<<(n + 255) / 256, 256, 0, stream>>>(deg, dinv, n);
    fill_kernel<<<eb, 256, 0, stream>>>(ei, flag, ofs, cnt, col, E);

    const int gb = (n + 63) / 64;
    const int ab = (n + 3) / 4;
    // layer 0: x -> h0(hs) -> h1(act)
    gemm_scale_kernel<<<gb, 128, 0, stream>>>(x, Wc0, dinv, h0, n);
    agg_kernel<<<ab, 256, 0, stream>>>(h0, dinv, ofs, col, bc0, h1, n, 1);
    // layer 1
    gemm_scale_kernel<<<gb, 128, 0, stream>>>(h1, Wc1, dinv, h0, n);
    agg_kernel<<<ab, 256, 0, stream>>>(h0, dinv, ofs, col, bc1, h1, n, 1);
    // layer 2 (no relu)
    gemm_scale_kernel<<<gb, 128, 0, stream>>>(h1, Wc2, dinv, h0, n);
    agg_kernel<<<ab, 256, 0, stream>>>(h0, dinv, ofs, col, bc2, h1, n, 0);

    boundary_kernel<<<(n + 255) / 256, 256, 0, stream>>>(bat, flag, gstart, n);
    pool_kernel<<<NGRAPH, 128, 0, stream>>>(h1, gstart, pooled);
    mlp_kernel<<<NGRAPH, 128, 0, stream>>>(pooled, W1, b1, W2, b2, out);
}

// Round 2
// 638.064 us; speedup vs baseline: 1.4822x; 1.4822x over previous
//
#include <hip/hip_runtime.h>
#include <hip/hip_bf16.h>
#include <stdint.h>

#define HID     128
#define OUTC    10
#define NGRAPH  512

using bf16x8 = __attribute__((ext_vector_type(8))) short;
using f32x4  = __attribute__((ext_vector_type(4))) float;

__device__ __forceinline__ short f2bf(float f) {
    __hip_bfloat16 h = __float2bfloat16(f);
    return *reinterpret_cast<short*>(&h);
}
__device__ __forceinline__ float bf2f(short s) {
    union { uint32_t u; float f; } x; x.u = ((uint32_t)(uint16_t)s) << 16; return x.f;
}
__device__ __forceinline__ float bflo(uint32_t v) {
    union { uint32_t u; float f; } x; x.u = v << 16; return x.f;
}
__device__ __forceinline__ float bfhi(uint32_t v) {
    union { uint32_t u; float f; } x; x.u = v & 0xffff0000u; return x.f;
}

// ---------------------------------------------------------------------------
// int64-vs-int32 layout detection (wave-parallel)
// ---------------------------------------------------------------------------
__global__ void detect64_kernel(const int* __restrict__ ei, int* __restrict__ flag) {
    int lane = threadIdx.x & 63;
    int v = ei[2 * lane + 1];
    unsigned long long b = __ballot(v == 0);
    if (threadIdx.x == 0) *flag = (b == ~0ULL) ? 1 : 0;
}

__device__ __forceinline__ int fetch_idx(const int* __restrict__ p, long j, int f64) {
    return p[f64 ? (j << 1) : j];
}

// ---------------------------------------------------------------------------
// CSR build: in-degree count, exclusive scan, scatter fill
// ---------------------------------------------------------------------------
__global__ void deg_kernel(const int* __restrict__ ei, const int* __restrict__ flag,
                           int* __restrict__ deg, long E) {
    long e = (long)blockIdx.x * blockDim.x + threadIdx.x;
    if (e >= E) return;
    int f = *flag;
    int d = fetch_idx(ei, E + e, f);
    atomicAdd(&deg[d], 1);
}

__global__ void __launch_bounds__(1024) scan_kernel(const int* __restrict__ deg,
                                                    int* __restrict__ ofs, int n) {
    __shared__ int wsum[16];
    __shared__ int carry_s;
    __shared__ int chunk_tot;
    const int tid  = threadIdx.x;
    const int lane = tid & 63;
    const int wid  = tid >> 6;
    if (tid == 0) carry_s = 0;
    __syncthreads();
    const int CHUNK = 4096;  // 1024 threads x 4
    for (int base = 0; base < n; base += CHUNK) {
        int idx = base + tid * 4;
        int v[4];
#pragma unroll
        for (int j = 0; j < 4; ++j) v[j] = (idx + j < n) ? deg[idx + j] : 0;
        int s1 = v[0] + v[1] + v[2] + v[3];
        int inc = s1;
#pragma unroll
        for (int d = 1; d < 64; d <<= 1) {
            int t = __shfl_up(inc, d, 64);
            if (lane >= d) inc += t;
        }
        if (lane == 63) wsum[wid] = inc;
        __syncthreads();
        if (wid == 0) {
            int ws = (lane < 16) ? wsum[lane] : 0;
            int winc = ws;
#pragma unroll
            for (int d = 1; d < 16; d <<= 1) {
                int t = __shfl_up(winc, d, 64);
                if (lane >= d) winc += t;
            }
            if (lane == 15) chunk_tot = winc;
            if (lane < 16) wsum[lane] = winc - ws;
        }
        __syncthreads();
        int excl = carry_s + wsum[wid] + (inc - s1);
        int run = excl;
#pragma unroll
        for (int j = 0; j < 4; ++j) {
            if (idx + j < n) ofs[idx + j] = run;
            run += v[j];
        }
        __syncthreads();
        if (tid == 0) carry_s += chunk_tot;
        __syncthreads();
    }
    if (tid == 0) ofs[n] = carry_s;
}

__global__ void dinv_kernel(const int* __restrict__ deg, float* __restrict__ dinv, int n) {
    int i = blockIdx.x * blockDim.x + threadIdx.x;
    if (i < n) dinv[i] = rsqrtf((float)deg[i] + 1.0f);
}

__global__ void fill_kernel(const int* __restrict__ ei, const int* __restrict__ flag,
                            const int* __restrict__ ofs, int* __restrict__ cnt,
                            int* __restrict__ col, long E) {
    long e = (long)blockIdx.x * blockDim.x + threadIdx.x;
    if (e >= E) return;
    int f = *flag;
    int s = fetch_idx(ei, e, f);
    int d = fetch_idx(ei, E + e, f);
    int pos = ofs[d] + atomicAdd(&cnt[d], 1);
    col[pos] = s;
}

// ---------------------------------------------------------------------------
// Weight prep: Wt[w] = transpose(W_w) split into bf16 hi + lo planes.
// Layout per weight: [hi: 128x128][lo: 128x128], row = output col, contiguous k.
// ---------------------------------------------------------------------------
__global__ void __launch_bounds__(128) wprep_kernel(
        const float* __restrict__ W0, const float* __restrict__ W1,
        const float* __restrict__ W2, short* __restrict__ Wt) {
    const float* W = (blockIdx.x == 0) ? W0 : (blockIdx.x == 1) ? W1 : W2;
    short* hi = Wt + (size_t)blockIdx.x * 2 * HID * HID;
    short* lo = hi + HID * HID;
    __shared__ float Ws[64][129];   // pad -> conflict-free transposed reads
    const int t = threadIdx.x;
    for (int half = 0; half < 2; ++half) {
        const int kbase = half * 64;
        // load 64 rows x 128 cols coalesced (float4)
#pragma unroll
        for (int it = 0; it < 16; ++it) {
            int idx = (t + it * 128) * 4;
            int k = idx >> 7, c = idx & 127;
            float4 v = *(const float4*)(W + (size_t)(kbase + k) * HID + c);
            Ws[k][c] = v.x; Ws[k][c + 1] = v.y; Ws[k][c + 2] = v.z; Ws[k][c + 3] = v.w;
        }
        __syncthreads();
        // write transposed, coalesced along k
        for (int it = 0; it < 64; ++it) {
            int k2 = t & 63;
            int c  = (t >> 6) + it * 2;
            float w = Ws[k2][c];
            short h = f2bf(w);
            hi[(size_t)c * HID + kbase + k2] = h;
            lo[(size_t)c * HID + kbase + k2] = f2bf(w - bf2f(h));
        }
        __syncthreads();
    }
}

// ---------------------------------------------------------------------------
// hs = bf16( (A @ W) * dinv[:,None] ) — MFMA bf16, LDS-free.
// Block = 256 thr = 4 waves, 128 rows x 128 cols, K=128.
// Wave w: cols [32w, 32w+32). Split-W (hi+lo) kills weight-quant error.
// ---------------------------------------------------------------------------
template<bool AFP32>
__global__ void __launch_bounds__(256) gemm_hs_kernel(
        const void* __restrict__ Ap, const short* __restrict__ Wt,
        const float* __restrict__ dinv, short* __restrict__ hs, int n) {
    const short* __restrict__ Bh = Wt;
    const short* __restrict__ Bl = Wt + HID * HID;
    const int tid = threadIdx.x;
    const int w  = tid >> 6;
    const int l  = tid & 63;
    const int lr = l & 15;   // A-row / B-col / D-col within fragment
    const int kq = l >> 4;   // k-quarter
    const int r0 = blockIdx.x * 128;

    f32x4 acc[8][2] = {};
    const int col0 = w * 32 + lr;
    const int col1 = w * 32 + 16 + lr;

    const float* Af = (const float*)Ap;
    const short* Ab = (const short*)Ap;

#pragma unroll
    for (int ks = 0; ks < 4; ++ks) {
        const int k0 = ks * 32 + kq * 8;
        bf16x8 a[8];
#pragma unroll
        for (int rf = 0; rf < 8; ++rf) {
            int row = r0 + rf * 16 + lr;
            if (row >= n) row = n - 1;      // loads clamped, stores guarded
            if (AFP32) {
                const float* ap = Af + (size_t)row * HID + k0;
                float4 f0 = *(const float4*)ap;
                float4 f1 = *(const float4*)(ap + 4);
                bf16x8 tv;
                tv[0] = f2bf(f0.x); tv[1] = f2bf(f0.y); tv[2] = f2bf(f0.z); tv[3] = f2bf(f0.w);
                tv[4] = f2bf(f1.x); tv[5] = f2bf(f1.y); tv[6] = f2bf(f1.z); tv[7] = f2bf(f1.w);
                a[rf] = tv;
            } else {
                a[rf] = *(const bf16x8*)(Ab + (size_t)row * HID + k0);
            }
        }
        bf16x8 bh0 = *(const bf16x8*)(Bh + (size_t)col0 * HID + k0);
        bf16x8 bh1 = *(const bf16x8*)(Bh + (size_t)col1 * HID + k0);
        bf16x8 bl0 = *(const bf16x8*)(Bl + (size_t)col0 * HID + k0);
        bf16x8 bl1 = *(const bf16x8*)(Bl + (size_t)col1 * HID + k0);
#pragma unroll
        for (int rf = 0; rf < 8; ++rf) {
            acc[rf][0] = __builtin_amdgcn_mfma_f32_16x16x32_bf16(a[rf], bh0, acc[rf][0], 0, 0, 0);
            acc[rf][1] = __builtin_amdgcn_mfma_f32_16x16x32_bf16(a[rf], bh1, acc[rf][1], 0, 0, 0);
            acc[rf][0] = __builtin_amdgcn_mfma_f32_16x16x32_bf16(a[rf], bl0, acc[rf][0], 0, 0, 0);
            acc[rf][1] = __builtin_amdgcn_mfma_f32_16x16x32_bf16(a[rf], bl1, acc[rf][1], 0, 0, 0);
        }
    }
    // D layout: col = lane&15, row = (lane>>4)*4 + reg  [m89-verified]
#pragma unroll
    for (int rf = 0; rf < 8; ++rf) {
#pragma unroll
        for (int rg = 0; rg < 4; ++rg) {
            int row = r0 + rf * 16 + kq * 4 + rg;
            if (row < n) {
                float dn = dinv[row];
                hs[(size_t)row * HID + col0] = f2bf(acc[rf][0][rg] * dn);
                hs[(size_t)row * HID + col1] = f2bf(acc[rf][1][rg] * dn);
            }
        }
    }
}

// ---------------------------------------------------------------------------
// out[d] = maybe_relu( dinv[d] * (hs[d] + sum_{e->d} hs[src]) + bias )  (bf16)
// one wave per node, lane = 2 channels (u32 = 2 bf16), edge loop 4x unrolled
// ---------------------------------------------------------------------------
__global__ void __launch_bounds__(256) agg_kernel(
        const short* __restrict__ hs, const float* __restrict__ dinv,
        const int* __restrict__ ofs, const int* __restrict__ col,
        const float* __restrict__ bias, short* __restrict__ out,
        int n, int do_relu) {
    int node = blockIdx.x * 4 + (threadIdx.x >> 6);
    if (node >= n) return;
    int lane = threadIdx.x & 63;
    const uint32_t* __restrict__ h2 = (const uint32_t*)hs;

    uint32_t sv = h2[(size_t)node * 64 + lane];
    float ax = bflo(sv), ay = bfhi(sv);
    int e0 = ofs[node], e1 = ofs[node + 1];
    int e = e0;
    for (; e + 4 <= e1; e += 4) {
        int s0 = col[e], s1 = col[e + 1], s2 = col[e + 2], s3 = col[e + 3];
        uint32_t v0 = h2[(size_t)s0 * 64 + lane];
        uint32_t v1 = h2[(size_t)s1 * 64 + lane];
        uint32_t v2 = h2[(size_t)s2 * 64 + lane];
        uint32_t v3 = h2[(size_t)s3 * 64 + lane];
        ax += bflo(v0) + bflo(v1) + bflo(v2) + bflo(v3);
        ay += bfhi(v0) + bfhi(v1) + bfhi(v2) + bfhi(v3);
    }
    for (; e < e1; ++e) {
        uint32_t v = h2[(size_t)col[e] * 64 + lane];
        ax += bflo(v); ay += bfhi(v);
    }
    float dn = dinv[node];
    float2 b = ((const float2*)bias)[lane];
    float ox = fmaf(ax, dn, b.x);
    float oy = fmaf(ay, dn, b.y);
    if (do_relu) { ox = fmaxf(ox, 0.f); oy = fmaxf(oy, 0.f); }
    uint32_t pk = (uint32_t)(uint16_t)f2bf(ox) | ((uint32_t)(uint16_t)f2bf(oy) << 16);
    ((uint32_t*)out)[(size_t)node * 64 + lane] = pk;
}

// ---------------------------------------------------------------------------
// pooling: batch sorted -> segment boundaries, then block-per-graph mean
// ---------------------------------------------------------------------------
__global__ void boundary_kernel(const int* __restrict__ batch, const int* __restrict__ flag,
                                int* __restrict__ gstart, int n) {
    int i = blockIdx.x * blockDim.x + threadIdx.x;
    if (i >= n) return;
    int f = *flag;
    int b  = fetch_idx(batch, i, f);
    int bp = (i == 0) ? -1 : fetch_idx(batch, i - 1, f);
    for (int g = bp + 1; g <= b; ++g) gstart[g] = i;
    if (i == n - 1) {
        for (int g = b + 1; g <= NGRAPH; ++g) gstart[g] = n;
    }
}

__global__ void __launch_bounds__(128) pool_kernel(const short* __restrict__ h,
                                                   const int* __restrict__ gstart,
                                                   float* __restrict__ pooled) {
    int g = blockIdx.x, c = threadIdx.x;
    int s = gstart[g], e = gstart[g + 1];
    float acc = 0.f;
    int i = s;
    for (; i + 4 <= e; i += 4) {
        acc += bf2f(h[(size_t)i * HID + c]) + bf2f(h[(size_t)(i + 1) * HID + c])
             + bf2f(h[(size_t)(i + 2) * HID + c]) + bf2f(h[(size_t)(i + 3) * HID + c]);
    }
    for (; i < e; ++i) acc += bf2f(h[(size_t)i * HID + c]);
    float cnt = (float)(e - s);
    pooled[g * HID + c] = acc / fmaxf(cnt, 1.f);
}

__global__ void __launch_bounds__(128) mlp_kernel(
        const float* __restrict__ pooled,
        const float* __restrict__ W1, const float* __restrict__ b1,
        const float* __restrict__ W2, const float* __restrict__ b2,
        float* __restrict__ out) {
    __shared__ float p[HID];
    __shared__ float hid[HID];
    int g = blockIdx.x, c = threadIdx.x;
    p[c] = pooled[g * HID + c];
    __syncthreads();
    float a = b1[c];
#pragma unroll 8
    for (int k = 0; k < HID; ++k) a = fmaf(p[k], W1[k * HID + c], a);
    hid[c] = fmaxf(a, 0.f);
    __syncthreads();
    if (c < OUTC) {
        float o = b2[c];
#pragma unroll 8
        for (int k = 0; k < HID; ++k) o = fmaf(hid[k], W2[k * OUTC + c], o);
        out[g * OUTC + c] = o;
    }
}

// ---------------------------------------------------------------------------
extern "C" void kernel_launch(void* const* d_in, const int* in_sizes, int n_in,
                              void* d_out, int out_size, void* d_ws, size_t ws_size,
                              hipStream_t stream) {
    const float* x   = (const float*)d_in[0];
    const int*   ei  = (const int*)d_in[1];
    const int*   bat = (const int*)d_in[2];
    const float* Wc0 = (const float*)d_in[3];
    const float* bc0 = (const float*)d_in[4];
    const float* Wc1 = (const float*)d_in[5];
    const float* bc1 = (const float*)d_in[6];
    const float* Wc2 = (const float*)d_in[7];
    const float* bc2 = (const float*)d_in[8];
    const float* W1  = (const float*)d_in[9];
    const float* b1  = (const float*)d_in[10];
    const float* W2  = (const float*)d_in[11];
    const float* b2  = (const float*)d_in[12];
    float* out = (float*)d_out;

    const int  n = in_sizes[0] / HID;
    const long E = in_sizes[1] / 2;

    char* w = (char*)d_ws;
    size_t off = 0;
    auto carve = [&](size_t bytes) {
        void* p = w + off;
        off += (bytes + 255) & ~(size_t)255;
        return p;
    };
    int*   flag   = (int*)carve(4);
    int*   deg    = (int*)carve((size_t)n * 4);
    int*   ofs    = (int*)carve((size_t)(n + 1) * 4);
    int*   cnt    = (int*)carve((size_t)n * 4);
    float* dinv   = (float*)carve((size_t)n * 4);
    int*   gstart = (int*)carve((NGRAPH + 1) * 4);
    int*   col    = (int*)carve((size_t)E * 4);
    short* Wt     = (short*)carve((size_t)3 * 2 * HID * HID * 2);
    short* hs     = (short*)carve((size_t)n * HID * 2);
    short* h      = (short*)carve((size_t)n * HID * 2);
    float* pooled = (float*)carve((size_t)NGRAPH * HID * 4);

    hipMemsetAsync(deg, 0, (size_t)n * 4, stream);
    hipMemsetAsync(cnt, 0, (size_t)n * 4, stream);

    detect64_kernel<<<1, 64, 0, stream>>>(ei, flag);

    const int eb = (int)((E + 255) / 256);
    deg_kernel<<<eb, 256, 0, stream>>>(ei, flag, deg, E);
    scan_kernel<<<1, 1024, 0, stream>>>(deg, ofs, n);
    dinv_kernel<<<(n + 255) / 256, 256, 0, stream>>>(deg, dinv, n);
    fill_kernel<<<eb, 256, 0, stream>>>(ei, flag, ofs, cnt, col, E);
    wprep_kernel<<<3, 128, 0, stream>>>(Wc0, Wc1, Wc2, Wt);

    const int gb = (n + 127) / 128;
    const int ab = (n + 3) / 4;
    const size_t WSTRIDE = (size_t)2 * HID * HID;
    // layer 0
    gemm_hs_kernel<true><<<gb, 256, 0, stream>>>(x, Wt, dinv, hs, n);
    agg_kernel<<<ab, 256, 0, stream>>>(hs, dinv, ofs, col, bc0, h, n, 1);
    // layer 1
    gemm_hs_kernel<false><<<gb, 256, 0, stream>>>(h, Wt + WSTRIDE, dinv, hs, n);
    agg_kernel<<<ab, 256, 0, stream>>>(hs, dinv, ofs, col, bc1, h, n, 1);
    // layer 2 (no relu)
    gemm_hs_kernel<false><<<gb, 256, 0, stream>>>(h, Wt + 2 * WSTRIDE, dinv, hs, n);
    agg_kernel<<<ab, 256, 0, stream>>>(hs, dinv, ofs, col, bc2, h, n, 0);

    boundary_kernel<<<(n + 255) / 256, 256, 0, stream>>>(bat, flag, gstart, n);
    pool_kernel<<<NGRAPH, 128, 0, stream>>>(h, gstart, pooled);
    mlp_kernel<<<NGRAPH, 128, 0, stream>>>(pooled, W1, b1, W2, b2, out);
}